// Round 6
// baseline (3116.269 us; speedup 1.0000x reference)
//
#include <hip/hip_runtime.h>
#include <hip/hip_fp16.h>
#include <cstdint>

typedef _Float16 half8 __attribute__((ext_vector_type(8)));
typedef _Float16 half4 __attribute__((ext_vector_type(4)));
typedef float f32x4 __attribute__((ext_vector_type(4)));

#define MFMA_F16 __builtin_amdgcn_mfma_f32_16x16x32_f16
#define PIN(x) asm volatile("" : "+v"(x))

__device__ __forceinline__ float fast_rcp(float x){
#if __has_builtin(__builtin_amdgcn_rcpf)
  return __builtin_amdgcn_rcpf(x);
#else
  return 1.0f/x;
#endif
}
__device__ __forceinline__ float fast_exp2(float x){
#if __has_builtin(__builtin_amdgcn_exp2f)
  return __builtin_amdgcn_exp2f(x);
#else
  return exp2f(x);
#endif
}
__device__ __forceinline__ float sigm_f(float x){
  return fast_rcp(1.0f + fast_exp2(-1.44269504f*x));
}
__device__ __forceinline__ float tanh_fast(float x){
  float e = fast_exp2(-2.88539008f*x);            // e^(-2x)
  return fmaf(2.0f, fast_rcp(1.0f + e), -1.0f);   // 2/(1+e) - 1
}

// ---------------------------------------------------------------------------
// Phase A1: per-matrix max|w| (4 matrices of 768x256)
// ---------------------------------------------------------------------------
__global__ __launch_bounds__(256) void k_maxabs(
    const float* __restrict__ w0, const float* __restrict__ w1,
    const float* __restrict__ w2, const float* __restrict__ w3,
    int n, int* __restrict__ slots)
{
  const float* srcs[4] = {w0, w1, w2, w3};
  int m    = blockIdx.x >> 5;   // 32 blocks per matrix
  int part = blockIdx.x & 31;
  const float* w = srcs[m];
  float loc = 0.0f;
  for (int i = part*256 + threadIdx.x; i < n; i += 32*256)
    loc = fmaxf(loc, fabsf(w[i]));
  for (int off = 32; off; off >>= 1)
    loc = fmaxf(loc, __shfl_down(loc, off, 64));
  __shared__ float red[4];
  int wv = threadIdx.x >> 6;
  if ((threadIdx.x & 63) == 0) red[wv] = loc;
  __syncthreads();
  if (threadIdx.x == 0) {
    float mx = fmaxf(fmaxf(red[0], red[1]), fmaxf(red[2], red[3]));
    atomicMax(&slots[m], __float_as_int(mx));
  }
}

// ---------------------------------------------------------------------------
// Phase A2: fake-quantize -> fp16 in MFMA-B-fragment-swizzled layout:
//   offset = (tile*8+kb)*512 + lane*8 + j
// ---------------------------------------------------------------------------
__global__ __launch_bounds__(256) void k_quant(
    const float* __restrict__ w0, const float* __restrict__ w1,
    const float* __restrict__ w2, const float* __restrict__ w3,
    const int* __restrict__ slots,
    _Float16* __restrict__ f0, _Float16* __restrict__ f1,
    _Float16* __restrict__ f2, _Float16* __restrict__ f3)
{
  const float* srcs[4] = {w0, w1, w2, w3};
  _Float16*    dsts[4] = {f0, f1, f2, f3};
  int idx = blockIdx.x*256 + threadIdx.x;       // 0 .. 786431
  int m = idx / 196608;
  int e = idx - m*196608;
  float scale = __int_as_float(slots[m]) * (1.0f/127.0f);
  float w = srcs[m][e];
  float q = rintf(w/scale) * scale;
  int g = e >> 8, k = e & 255;
  int tile = g >> 4, kb = k >> 5;
  int lane = ((k >> 3) & 3)*16 + (g & 15);
  int off  = (tile*8 + kb)*512 + lane*8 + (k & 7);
  dsts[m][off] = (_Float16)q;
}

// ---------------------------------------------------------------------------
// gi layout (consumer-ordered, gate-packed):
//   chunk(t, jw, bb) = ((t*16 + jw)*16 + bb), 768 halves per chunk.
//   lane l, gate g: chunk*768 + l*12 + g*4  (half4 per gate)
// bR,bZ (= b_hh r/z) folded into GEMM bias; bN is not (inside r*(...)).
// ---------------------------------------------------------------------------

// Fat GEMM (f32 A = x): gi = x @ Wq^T + b_ih (+ b_hh for r,z), gi layout.
__global__ __launch_bounds__(256) void k_gemm_f32(
    const float* __restrict__ A, const _Float16* __restrict__ Wf,
    const float* __restrict__ bih, const float* __restrict__ bhh,
    _Float16* __restrict__ gi)
{
  __shared__ _Float16 Al[16384];                // 4 bands x 8 kb x 512 halves
  const int tid = threadIdx.x;
  const long r0 = (long)blockIdx.x * 64;
  const int by  = blockIdx.y;                   // 6 col-blocks of 128

  const float4* A4 = (const float4*)A;
  #pragma unroll
  for (int p = 0; p < 16; p++) {
    int n = p*256 + tid;
    int row = n >> 6, f4 = n & 63, k0 = f4*4;
    float4 v = A4[(r0 + row)*64 + f4];
    int lane = ((k0 >> 3) & 3)*16 + (row & 15);
    _Float16* d = &Al[((row >> 4)*8 + (k0 >> 5))*512 + lane*8 + (k0 & 7)];
    d[0] = (_Float16)v.x; d[1] = (_Float16)v.y;
    d[2] = (_Float16)v.z; d[3] = (_Float16)v.w;
  }
  __syncthreads();

  const int w = tid >> 6, l = tid & 63, c16 = l & 15;
  f32x4 acc[8];
  #pragma unroll
  for (int nt = 0; nt < 8; nt++) acc[nt] = (f32x4){0.f, 0.f, 0.f, 0.f};
  float bv[8];
  #pragma unroll
  for (int nt = 0; nt < 8; nt++) {
    int col = by*128 + nt*16 + c16;             // 0..767
    bv[nt] = bih[col] + (col < 512 ? bhh[col] : 0.0f);
  }

  #pragma unroll
  for (int kb = 0; kb < 8; kb++) {
    half8 a = *(const half8*)&Al[(w*8 + kb)*512 + l*8];
    #pragma unroll
    for (int nt = 0; nt < 8; nt++) {
      half8 b = *(const half8*)&Wf[((size_t)((by*8 + nt)*8 + kb))*512 + l*8];
      acc[nt] = MFMA_F16(a, b, acc[nt], 0, 0, 0);
    }
  }

  const int t = (int)(r0 >> 8);
  const int bb = ((int)(r0 & 255) >> 4) + w;
  #pragma unroll
  for (int nt = 0; nt < 8; nt++) {
    int cj = by*8 + nt;                         // 16-col group index (0..47)
    int g  = cj >> 4, jw = cj & 15;
    size_t chunk = ((size_t)t*16 + jw)*16 + bb;
    half4 v;
    #pragma unroll
    for (int i = 0; i < 4; i++) v[i] = (_Float16)(acc[nt][i] + bv[nt]);
    *(half4*)&gi[chunk*768 + l*12 + g*4] = v;
  }
}

// Fat GEMM (A = hseq in frag layout): direct A-frag global loads, no LDS.
__global__ __launch_bounds__(256) void k_gemm_h(
    const _Float16* __restrict__ hseq, const _Float16* __restrict__ Wf,
    const float* __restrict__ bih, const float* __restrict__ bhh,
    _Float16* __restrict__ gi)
{
  const int tid = threadIdx.x;
  const long r0 = (long)blockIdx.x * 64;
  const int by  = blockIdx.y;

  const int w = tid >> 6, l = tid & 63, c16 = l & 15;
  const int t = (int)(r0 >> 8);
  const int bb = ((int)(r0 & 255) >> 4) + w;

  f32x4 acc[8];
  #pragma unroll
  for (int nt = 0; nt < 8; nt++) acc[nt] = (f32x4){0.f, 0.f, 0.f, 0.f};
  float bv[8];
  #pragma unroll
  for (int nt = 0; nt < 8; nt++) {
    int col = by*128 + nt*16 + c16;
    bv[nt] = bih[col] + (col < 512 ? bhh[col] : 0.0f);
  }

  #pragma unroll
  for (int kb = 0; kb < 8; kb++) {
    half8 a = *(const half8*)&hseq[(((size_t)t*16 + bb)*8 + kb)*512 + l*8];
    #pragma unroll
    for (int nt = 0; nt < 8; nt++) {
      half8 b = *(const half8*)&Wf[((size_t)((by*8 + nt)*8 + kb))*512 + l*8];
      acc[nt] = MFMA_F16(a, b, acc[nt], 0, 0, 0);
    }
  }

  #pragma unroll
  for (int nt = 0; nt < 8; nt++) {
    int cj = by*8 + nt;
    int g  = cj >> 4, jw = cj & 15;
    size_t chunk = ((size_t)t*16 + jw)*16 + bb;
    half4 v;
    #pragma unroll
    for (int i = 0; i < 4; i++) v[i] = (_Float16)(acc[nt][i] + bv[nt]);
    *(half4*)&gi[chunk*768 + l*12 + g*4] = v;
  }
}

// ---------------------------------------------------------------------------
// Serial GRU: 16 blocks x 512 thr (8 waves), __launch_bounds__(512,2)
// -> 256 arch-VGPR cap. ALL 48 W_hh fragments (192 VGPRs) pinned resident.
// Wave w owns col tiles {w, w+8} per gate (cols j, j+128). LDS: 16 KB h dbuf.
// ---------------------------------------------------------------------------
__global__ __launch_bounds__(512, 2) void k_gru(
    const _Float16* __restrict__ gi, const _Float16* __restrict__ Wf,
    const float* __restrict__ bhh, float* __restrict__ hcarry,
    _Float16* __restrict__ hseq, int Csteps)
{
  __shared__ _Float16 hl[2][4096];              // 16 KB frag-ordered h (dbuf)
  const int tid = threadIdx.x;
  const int bb  = blockIdx.x;
  const int b0  = bb * 16;

  { // stage initial h (f32 carry -> fp16 frags), 8 halves per thread
    int n = tid*8;
    int b = n >> 8, k0 = n & 255;               // 8-aligned within 32 ✓
    float4 v0 = *(const float4*)&hcarry[(size_t)(b0 + b)*256 + k0];
    float4 v1 = *(const float4*)&hcarry[(size_t)(b0 + b)*256 + k0 + 4];
    half8 hv;
    hv[0]=(_Float16)v0.x; hv[1]=(_Float16)v0.y; hv[2]=(_Float16)v0.z; hv[3]=(_Float16)v0.w;
    hv[4]=(_Float16)v1.x; hv[5]=(_Float16)v1.y; hv[6]=(_Float16)v1.z; hv[7]=(_Float16)v1.w;
    int lane = ((k0 >> 3) & 3)*16 + b;
    *(half8*)&hl[0][(k0 >> 5)*512 + lane*8] = hv;
  }

  const int w = tid >> 6, l = tid & 63, q = l >> 4, c16 = l & 15;
  const int j1 = w*16 + c16;                    // sub 0 column
  const float bN[2] = { bhh[512 + j1], bhh[512 + j1 + 128] };
  float hprev[2][4];
  #pragma unroll
  for (int s = 0; s < 2; s++)
    #pragma unroll
    for (int i = 0; i < 4; i++)
      hprev[s][i] = hcarry[(size_t)(b0 + q*4 + i)*256 + j1 + s*128];

  // ---- preload + PIN all 48 weight fragments ----
  half8 wr[2][8], wz[2][8], wn[2][8];
  #pragma unroll
  for (int s = 0; s < 2; s++) {
    const _Float16* WR = Wf + (size_t)(s*8 + w)      *4096;
    const _Float16* WZ = Wf + (size_t)(16 + s*8 + w) *4096;
    const _Float16* WN = Wf + (size_t)(32 + s*8 + w) *4096;
    #pragma unroll
    for (int kb = 0; kb < 8; kb++) {
      wr[s][kb] = *(const half8*)&WR[(kb*64 + l)*8];  PIN(wr[s][kb]);
      wz[s][kb] = *(const half8*)&WZ[(kb*64 + l)*8];  PIN(wz[s][kb]);
      wn[s][kb] = *(const half8*)&WN[(kb*64 + l)*8];  PIN(wn[s][kb]);
    }
  }

  const int wr_off = (j1 >> 5)*512 + ((j1 >> 3) & 3)*128 + (j1 & 7);
  const _Float16* gp0 = gi + ((size_t)(w*16      + bb))*768 + l*12;
  const _Float16* gp1 = gi + ((size_t)((w+8)*16  + bb))*768 + l*12;
  _Float16* hq = hseq ? hseq + (size_t)bb*4096 + tid*8 : (_Float16*)nullptr;

  __syncthreads();
  int cur = 0;
  for (int t = 0; t < Csteps; t++) {
    half4 vR0 = *(const half4*)(gp0);
    half4 vZ0 = *(const half4*)(gp0 + 4);
    half4 vN0 = *(const half4*)(gp0 + 8);
    half4 vR1 = *(const half4*)(gp1);
    half4 vZ1 = *(const half4*)(gp1 + 4);
    half4 vN1 = *(const half4*)(gp1 + 8);
    gp0 += 196608; gp1 += 196608;

    f32x4 aR[2], aZ[2], aN[2];
    #pragma unroll
    for (int s = 0; s < 2; s++) {
      aR[s] = (f32x4){0.f,0.f,0.f,0.f};
      aZ[s] = (f32x4){0.f,0.f,0.f,0.f};
      aN[s] = (f32x4){0.f,0.f,0.f,0.f};
    }
    #pragma unroll
    for (int kb = 0; kb < 8; kb++) {
      half8 a = *(const half8*)&hl[cur][kb*512 + l*8];
      #pragma unroll
      for (int s = 0; s < 2; s++) {
        aR[s] = MFMA_F16(a, wr[s][kb], aR[s], 0, 0, 0);
        aZ[s] = MFMA_F16(a, wz[s][kb], aZ[s], 0, 0, 0);
        aN[s] = MFMA_F16(a, wn[s][kb], aN[s], 0, 0, 0);
      }
    }

    const int nxt = cur ^ 1;
    #pragma unroll
    for (int s = 0; s < 2; s++) {
      half4 vR = s ? vR1 : vR0, vZ = s ? vZ1 : vZ0, vN = s ? vN1 : vN0;
      #pragma unroll
      for (int i = 0; i < 4; i++) {
        float r  = sigm_f(aR[s][i] + (float)vR[i]);
        float z  = sigm_f(aZ[s][i] + (float)vZ[i]);
        float nn = tanh_fast((float)vN[i] + r*(aN[s][i] + bN[s]));
        float hp = nn + z*(hprev[s][i] - nn);   // (1-z)*n + z*h
        hprev[s][i] = hp;
        hl[nxt][wr_off + s*2048 + (q*4 + i)*8] = (_Float16)hp;
      }
    }
    __syncthreads();
    if (hq) {
      *(half8*)hq = *(const half8*)&hl[nxt][tid*8];
      hq += 65536;
    }
    cur ^= 1;
  }

  #pragma unroll
  for (int s = 0; s < 2; s++)
    #pragma unroll
    for (int i = 0; i < 4; i++)
      hcarry[(size_t)(b0 + q*4 + i)*256 + j1 + s*128] = hprev[s][i];
}

// ---------------------------------------------------------------------------
extern "C" void kernel_launch(void* const* d_in, const int* in_sizes, int n_in,
                              void* d_out, int out_size, void* d_ws, size_t ws_size,
                              hipStream_t stream)
{
  const float* x     = (const float*)d_in[0];
  const float* h1_0  = (const float*)d_in[1];
  const float* h2_0  = (const float*)d_in[2];
  const float* w_ih1 = (const float*)d_in[3];
  const float* w_hh1 = (const float*)d_in[4];
  const float* b_ih1 = (const float*)d_in[5];
  const float* b_hh1 = (const float*)d_in[6];
  const float* w_ih2 = (const float*)d_in[7];
  const float* w_hh2 = (const float*)d_in[8];
  const float* b_ih2 = (const float*)d_in[9];
  const float* b_hh2 = (const float*)d_in[10];

  char* ws = (char*)d_ws;
  size_t off = 0;
  auto alloc = [&](size_t bytes) -> void* {
    void* p = ws + off; off += (bytes + 255) & ~(size_t)255; return p;
  };
  int*      slots   = (int*)     alloc(16);
  _Float16* wf_ih1  = (_Float16*)alloc(196608*2);
  _Float16* wf_hh1  = (_Float16*)alloc(196608*2);
  _Float16* wf_ih2  = (_Float16*)alloc(196608*2);
  _Float16* wf_hh2  = (_Float16*)alloc(196608*2);
  float*    hc1     = (float*)   alloc(256*256*4);
  float*    hc2     = (float*)   alloc(256*256*4);

  size_t fixed = off;
  int C = 512;
  while (C > 4 && fixed + (size_t)C*917504 + 1024 > ws_size) C >>= 1;
  _Float16* gi1   = (_Float16*)alloc((size_t)C*393216);
  _Float16* gi2   = (_Float16*)alloc((size_t)C*393216);
  _Float16* h1seq = (_Float16*)alloc((size_t)C*131072);
  const int nchunks = 512 / C;

  k_maxabs<<<128, 256, 0, stream>>>(w_ih1, w_hh1, w_ih2, w_hh2, 196608, slots);
  k_quant <<<3072, 256, 0, stream>>>(w_ih1, w_hh1, w_ih2, w_hh2, slots,
                                     wf_ih1, wf_hh1, wf_ih2, wf_hh2);
  (void)hipMemcpyAsync(hc1, h1_0, 256*256*4, hipMemcpyDeviceToDevice, stream);
  (void)hipMemcpyAsync(hc2, h2_0, 256*256*4, hipMemcpyDeviceToDevice, stream);

  for (int c = 0; c < nchunks; c++) {
    const float* xc = x + (size_t)c*C*65536;
    dim3 gg(C*256/64, 6);
    k_gemm_f32<<<gg, 256, 0, stream>>>(xc, wf_ih1, b_ih1, b_hh1, gi1);
    k_gru<<<16, 512, 0, stream>>>(gi1, wf_hh1, b_hh1, hc1, h1seq, C);
    k_gemm_h<<<gg, 256, 0, stream>>>(h1seq, wf_ih2, b_ih2, b_hh2, gi2);
    k_gru<<<16, 512, 0, stream>>>(gi2, wf_hh2, b_hh2, hc2, (_Float16*)nullptr, C);
  }

  (void)hipMemcpyAsync(d_out, hc2, 256*256*4, hipMemcpyDeviceToDevice, stream);
}

// Round 7
// 1861.510 us; speedup vs baseline: 1.6741x; 1.6741x over previous
//
#include <hip/hip_runtime.h>
#include <hip/hip_fp16.h>
#include <cstdint>

typedef _Float16 half8 __attribute__((ext_vector_type(8)));
typedef _Float16 half4 __attribute__((ext_vector_type(4)));
typedef float f32x4 __attribute__((ext_vector_type(4)));

#define MFMA_F16 __builtin_amdgcn_mfma_f32_16x16x32_f16
#define PIN(x) asm volatile("" : "+v"(x))
#define LD_RLX(p)   __hip_atomic_load((p),  __ATOMIC_RELAXED, __HIP_MEMORY_SCOPE_AGENT)
#define LD_ACQ(p)   __hip_atomic_load((p),  __ATOMIC_ACQUIRE, __HIP_MEMORY_SCOPE_AGENT)
#define ST_REL(p,v) __hip_atomic_store((p),(v), __ATOMIC_RELEASE, __HIP_MEMORY_SCOPE_AGENT)

__device__ __forceinline__ float fast_rcp(float x){
#if __has_builtin(__builtin_amdgcn_rcpf)
  return __builtin_amdgcn_rcpf(x);
#else
  return 1.0f/x;
#endif
}
__device__ __forceinline__ float fast_exp2(float x){
#if __has_builtin(__builtin_amdgcn_exp2f)
  return __builtin_amdgcn_exp2f(x);
#else
  return exp2f(x);
#endif
}
__device__ __forceinline__ float sigm_f(float x){
  return fast_rcp(1.0f + fast_exp2(-1.44269504f*x));
}
__device__ __forceinline__ float tanh_fast(float x){
  float e = fast_exp2(-2.88539008f*x);            // e^(-2x)
  return fmaf(2.0f, fast_rcp(1.0f + e), -1.0f);   // 2/(1+e) - 1
}

// ---------------------------------------------------------------------------
// Phase A1: per-matrix max|w| (4 matrices of 768x256)
// ---------------------------------------------------------------------------
__global__ __launch_bounds__(256) void k_maxabs(
    const float* __restrict__ w0, const float* __restrict__ w1,
    const float* __restrict__ w2, const float* __restrict__ w3,
    int n, int* __restrict__ slots)
{
  const float* srcs[4] = {w0, w1, w2, w3};
  int m    = blockIdx.x >> 5;
  int part = blockIdx.x & 31;
  const float* w = srcs[m];
  float loc = 0.0f;
  for (int i = part*256 + threadIdx.x; i < n; i += 32*256)
    loc = fmaxf(loc, fabsf(w[i]));
  for (int off = 32; off; off >>= 1)
    loc = fmaxf(loc, __shfl_down(loc, off, 64));
  __shared__ float red[4];
  int wv = threadIdx.x >> 6;
  if ((threadIdx.x & 63) == 0) red[wv] = loc;
  __syncthreads();
  if (threadIdx.x == 0) {
    float mx = fmaxf(fmaxf(red[0], red[1]), fmaxf(red[2], red[3]));
    atomicMax(&slots[m], __float_as_int(mx));
  }
}

// ---------------------------------------------------------------------------
// Phase A2: fake-quantize -> fp16, MFMA-B-fragment-swizzled layout.
// ---------------------------------------------------------------------------
__global__ __launch_bounds__(256) void k_quant(
    const float* __restrict__ w0, const float* __restrict__ w1,
    const float* __restrict__ w2, const float* __restrict__ w3,
    const int* __restrict__ slots,
    _Float16* __restrict__ f0, _Float16* __restrict__ f1,
    _Float16* __restrict__ f2, _Float16* __restrict__ f3)
{
  const float* srcs[4] = {w0, w1, w2, w3};
  _Float16*    dsts[4] = {f0, f1, f2, f3};
  int idx = blockIdx.x*256 + threadIdx.x;
  int m = idx / 196608;
  int e = idx - m*196608;
  float scale = __int_as_float(slots[m]) * (1.0f/127.0f);
  float w = srcs[m][e];
  float q = rintf(w/scale) * scale;
  int g = e >> 8, k = e & 255;
  int tile = g >> 4, kb = k >> 5;
  int lane = ((k >> 3) & 3)*16 + (g & 15);
  int off  = (tile*8 + kb)*512 + lane*8 + (k & 7);
  dsts[m][off] = (_Float16)q;
}

// ---------------------------------------------------------------------------
// gi layout: chunk(t,jw,bb) = ((t*16+jw)*16+bb)*768 + l*12 + gate*4
// bR,bZ (b_hh r/z) folded into GEMM bias; bN is not (inside r*(...)).
// ---------------------------------------------------------------------------
__global__ __launch_bounds__(256) void k_gemm_f32(
    const float* __restrict__ A, const _Float16* __restrict__ Wf,
    const float* __restrict__ bih, const float* __restrict__ bhh,
    _Float16* __restrict__ gi)
{
  __shared__ _Float16 Al[16384];
  const int tid = threadIdx.x;
  const long r0 = (long)blockIdx.x * 64;
  const int by  = blockIdx.y;

  const float4* A4 = (const float4*)A;
  #pragma unroll
  for (int p = 0; p < 16; p++) {
    int n = p*256 + tid;
    int row = n >> 6, f4 = n & 63, k0 = f4*4;
    float4 v = A4[(r0 + row)*64 + f4];
    int lane = ((k0 >> 3) & 3)*16 + (row & 15);
    _Float16* d = &Al[((row >> 4)*8 + (k0 >> 5))*512 + lane*8 + (k0 & 7)];
    d[0] = (_Float16)v.x; d[1] = (_Float16)v.y;
    d[2] = (_Float16)v.z; d[3] = (_Float16)v.w;
  }
  __syncthreads();

  const int w = tid >> 6, l = tid & 63, c16 = l & 15;
  f32x4 acc[8];
  #pragma unroll
  for (int nt = 0; nt < 8; nt++) acc[nt] = (f32x4){0.f, 0.f, 0.f, 0.f};
  float bv[8];
  #pragma unroll
  for (int nt = 0; nt < 8; nt++) {
    int col = by*128 + nt*16 + c16;
    bv[nt] = bih[col] + (col < 512 ? bhh[col] : 0.0f);
  }

  #pragma unroll
  for (int kb = 0; kb < 8; kb++) {
    half8 a = *(const half8*)&Al[(w*8 + kb)*512 + l*8];
    #pragma unroll
    for (int nt = 0; nt < 8; nt++) {
      half8 b = *(const half8*)&Wf[((size_t)((by*8 + nt)*8 + kb))*512 + l*8];
      acc[nt] = MFMA_F16(a, b, acc[nt], 0, 0, 0);
    }
  }

  const int t = (int)(r0 >> 8);
  const int bb = ((int)(r0 & 255) >> 4) + w;
  #pragma unroll
  for (int nt = 0; nt < 8; nt++) {
    int cj = by*8 + nt;
    int g  = cj >> 4, jw = cj & 15;
    size_t chunk = ((size_t)t*16 + jw)*16 + bb;
    half4 v;
    #pragma unroll
    for (int i = 0; i < 4; i++) v[i] = (_Float16)(acc[nt][i] + bv[nt]);
    *(half4*)&gi[chunk*768 + l*12 + g*4] = v;
  }
}

// ---------------------------------------------------------------------------
// Fused pipeline kernel: 64 blocks x 1024 thr.
//   role 0..15  : layer-1 GRU (R5 body), publishes h1seq via flag1 / 16 steps
//   role 16..31 : layer-2 GRU (R5 body), acquires gi2 via flag2, publishes
//                 consumption progress flag3 (back-pressure for gi2 ring)
//   role 32..63 : gemm2 producers: h1seq @ W_ih2^T + bias -> gi2 ring.
//                 2 blocks per batch-group, alternating 16-step groups.
// gi2 is a 64-step ring (25 MB). Flags in d_ws: poison (0xAA..)=negative
// = "not ready"; producers store absolute counts.
// ---------------------------------------------------------------------------
__global__ __launch_bounds__(1024, 4) void k_pipe(
    const _Float16* __restrict__ gi1, const _Float16* __restrict__ wfhh1,
    const float* __restrict__ bhh1, float* __restrict__ hc1,
    _Float16* __restrict__ h1seq,
    const _Float16* __restrict__ wfih2, const float* __restrict__ bih2,
    const float* __restrict__ bhh2, const _Float16* __restrict__ wfhh2,
    float* __restrict__ hc2, _Float16* __restrict__ gi2,
    int* __restrict__ flag1, int* __restrict__ flag2, int* __restrict__ flag3)
{
  __shared__ _Float16 hl[2][4096];              // 16 KB h dbuf (gru roles)
  __shared__ _Float16 wn_l[24576];              // 48 KB: 16 waves x 3 kb x 512
  const int role = blockIdx.x;
  const int tid  = threadIdx.x;
  const int w = tid >> 6, l = tid & 63, q = l >> 4, c16 = l & 15;

  if (role >= 32) {
    // ------------------- gemm2 producer -------------------
    const int id = role - 32, bb = id >> 1, par = id & 1;
    const int j = w*16 + c16;
    const float bR = bih2[j]       + bhh2[j];
    const float bZ = bih2[256 + j] + bhh2[256 + j];
    const float bN = bih2[512 + j];
    const _Float16* WR = wfih2 + (size_t)(w)      *4096;
    const _Float16* WZ = wfih2 + (size_t)(16 + w) *4096;
    const _Float16* WN = wfih2 + (size_t)(32 + w) *4096;
    half8 wr[8], wz[8], wn[5];
    #pragma unroll
    for (int kb = 0; kb < 8; kb++) {
      wr[kb] = *(const half8*)&WR[(kb*64 + l)*8];  PIN(wr[kb]);
      wz[kb] = *(const half8*)&WZ[(kb*64 + l)*8];  PIN(wz[kb]);
    }
    #pragma unroll
    for (int i = 0; i < 5; i++) {
      wn[i] = *(const half8*)&WN[((i + 3)*64 + l)*8];  PIN(wn[i]);
    }
    #pragma unroll
    for (int kb = 0; kb < 3; kb++)
      *(half8*)&wn_l[(w*3 + kb)*512 + l*8] = *(const half8*)&WN[(kb*64 + l)*8];
    __syncthreads();

    for (int g = par; g < 32; g += 2) {
      const int t0 = g*16;
      if (tid == 0) {
        while (LD_RLX(&flag1[bb]) < t0 + 16) __builtin_amdgcn_s_sleep(10);
        if (g >= 4)
          while (LD_RLX(&flag3[bb]) < (g - 3)*16) __builtin_amdgcn_s_sleep(10);
        (void)LD_ACQ(&flag1[bb]);               // acquire: invalidate caches
      }
      __syncthreads();
      for (int t = t0; t < t0 + 16; t++) {
        const _Float16* ap = h1seq + (size_t)t*65536 + (size_t)bb*4096 + l*8;
        f32x4 aR = (f32x4){0.f,0.f,0.f,0.f};
        f32x4 aZ = (f32x4){0.f,0.f,0.f,0.f};
        f32x4 aN = (f32x4){0.f,0.f,0.f,0.f};
        #pragma unroll
        for (int kb = 0; kb < 8; kb++) {
          half8 a  = *(const half8*)&ap[kb*512];
          half8 bn = (kb < 3) ? *(const half8*)&wn_l[(w*3 + kb)*512 + l*8]
                              : wn[kb - 3];
          aR = MFMA_F16(a, wr[kb], aR, 0, 0, 0);
          aZ = MFMA_F16(a, wz[kb], aZ, 0, 0, 0);
          aN = MFMA_F16(a, bn,     aN, 0, 0, 0);
        }
        _Float16* op = gi2 + ((size_t)(t & 63)*256 + w*16 + bb)*768 + l*12;
        half4 vR, vZ, vN;
        #pragma unroll
        for (int i = 0; i < 4; i++) {
          vR[i] = (_Float16)(aR[i] + bR);
          vZ[i] = (_Float16)(aZ[i] + bZ);
          vN[i] = (_Float16)(aN[i] + bN);
        }
        *(half4*)(op)     = vR;
        *(half4*)(op + 4) = vZ;
        *(half4*)(op + 8) = vN;
      }
      __syncthreads();                          // drains all waves' stores
      if (tid == 0) ST_REL(&flag2[bb*2 + par], t0 + 16);
    }
    return;
  }

  // ------------------- GRU roles -------------------
  const bool L1 = (role < 16);
  const int bb = L1 ? role : role - 16;
  const int b0 = bb * 16;
  const _Float16* gi = L1 ? gi1 : gi2;
  const _Float16* Wf = L1 ? wfhh1 : wfhh2;
  const float* bhh   = L1 ? bhh1 : bhh2;
  float* hcarry      = L1 ? hc1 : hc2;

  { // stage initial h (f32 carry -> fp16 frags)
    int n = tid*4;
    int b = n >> 8, k = n & 255;
    float4 v = *(const float4*)&hcarry[(size_t)(b0 + b)*256 + k];
    _Float16* d = &hl[0][(k >> 5)*512 + (((k >> 3) & 3)*16 + b)*8 + (k & 7)];
    d[0] = (_Float16)v.x; d[1] = (_Float16)v.y;
    d[2] = (_Float16)v.z; d[3] = (_Float16)v.w;
  }

  const int j = w*16 + c16;
  const float bN = bhh[512 + j];
  float hprev[4];
  #pragma unroll
  for (int i = 0; i < 4; i++)
    hprev[i] = hcarry[(size_t)(b0 + q*4 + i)*256 + j];

  const _Float16* WR = Wf + (size_t)(w)      *4096;
  const _Float16* WZ = Wf + (size_t)(16 + w) *4096;
  const _Float16* WN = Wf + (size_t)(32 + w) *4096;
  half8 wr[8], wz[8], wn[5];
  #pragma unroll
  for (int kb = 0; kb < 8; kb++) {
    wr[kb] = *(const half8*)&WR[(kb*64 + l)*8];  PIN(wr[kb]);
    wz[kb] = *(const half8*)&WZ[(kb*64 + l)*8];  PIN(wz[kb]);
  }
  #pragma unroll
  for (int i = 0; i < 5; i++) {
    wn[i] = *(const half8*)&WN[((i + 3)*64 + l)*8];  PIN(wn[i]);
  }
  #pragma unroll
  for (int kb = 0; kb < 3; kb++)
    *(half8*)&wn_l[(w*3 + kb)*512 + l*8] = *(const half8*)&WN[(kb*64 + l)*8];

  const int wr_off = (j >> 5)*512 + ((j >> 3) & 3)*128 + (j & 7);
  const size_t gi_lane = (size_t)(w*16 + bb)*768 + l*12;
  _Float16* hq = L1 ? (h1seq + (size_t)bb*4096 + tid*4) : (_Float16*)nullptr;

  __syncthreads();
  int cur = 0;
  for (int t = 0; t < 512; t++) {
    if (!L1 && (t & 15) == 0) {                 // acquire gi2 group
      if (tid == 0) {
        int* f = &flag2[bb*2 + ((t >> 4) & 1)];
        while (LD_RLX(f) < t + 16) __builtin_amdgcn_s_sleep(10);
        (void)LD_ACQ(f);
      }
      __syncthreads();
    }
    const int tm = L1 ? t : (t & 63);
    const _Float16* gp = gi + (size_t)tm*196608 + gi_lane;
    half4 vR = *(const half4*)(gp);
    half4 vZ = *(const half4*)(gp + 4);
    half4 vN = *(const half4*)(gp + 8);

    f32x4 aR = (f32x4){0.f,0.f,0.f,0.f};
    f32x4 aZ = (f32x4){0.f,0.f,0.f,0.f};
    f32x4 aN = (f32x4){0.f,0.f,0.f,0.f};
    #pragma unroll
    for (int kb = 0; kb < 8; kb++) {
      half8 a  = *(const half8*)&hl[cur][kb*512 + l*8];
      half8 bn = (kb < 3) ? *(const half8*)&wn_l[(w*3 + kb)*512 + l*8]
                          : wn[kb - 3];
      aR = MFMA_F16(a, wr[kb], aR, 0, 0, 0);
      aZ = MFMA_F16(a, wz[kb], aZ, 0, 0, 0);
      aN = MFMA_F16(a, bn,     aN, 0, 0, 0);
    }

    const int nxt = cur ^ 1;
    #pragma unroll
    for (int i = 0; i < 4; i++) {
      float r  = sigm_f(aR[i] + (float)vR[i]);
      float z  = sigm_f(aZ[i] + (float)vZ[i]);
      float nn = tanh_fast((float)vN[i] + r*(aN[i] + bN));
      float hp = nn + z*(hprev[i] - nn);        // (1-z)*n + z*h
      hprev[i] = hp;
      hl[nxt][wr_off + (q*4 + i)*8] = (_Float16)hp;
    }
    __syncthreads();                            // drains hq(t-1) stores too
    if (tid == 0 && (t & 15) == 0 && t > 0) {
      if (L1) ST_REL(&flag1[bb], t);            // steps 0..t-1 published
      else    ST_REL(&flag3[bb], t);            // steps 0..t-1 consumed
    }
    if (L1)
      *(half4*)&hq[(size_t)t*65536] = *(const half4*)&hl[nxt][tid*4];
    cur ^= 1;
  }
  __syncthreads();                              // drain hq(511)
  if (tid == 0) {
    if (L1) ST_REL(&flag1[bb], 512);
    else    ST_REL(&flag3[bb], 512);
  }

  #pragma unroll
  for (int i = 0; i < 4; i++)
    hcarry[(size_t)(b0 + q*4 + i)*256 + j] = hprev[i];
}

// ---------------------------------------------------------------------------
extern "C" void kernel_launch(void* const* d_in, const int* in_sizes, int n_in,
                              void* d_out, int out_size, void* d_ws, size_t ws_size,
                              hipStream_t stream)
{
  const float* x     = (const float*)d_in[0];
  const float* h1_0  = (const float*)d_in[1];
  const float* h2_0  = (const float*)d_in[2];
  const float* w_ih1 = (const float*)d_in[3];
  const float* w_hh1 = (const float*)d_in[4];
  const float* b_ih1 = (const float*)d_in[5];
  const float* b_hh1 = (const float*)d_in[6];
  const float* w_ih2 = (const float*)d_in[7];
  const float* w_hh2 = (const float*)d_in[8];
  const float* b_ih2 = (const float*)d_in[9];
  const float* b_hh2 = (const float*)d_in[10];

  char* ws = (char*)d_ws;
  size_t off = 0;
  auto alloc = [&](size_t bytes) -> void* {
    void* p = ws + off; off += (bytes + 255) & ~(size_t)255; return p;
  };
  int*      slots   = (int*)     alloc(16);
  _Float16* wf_ih1  = (_Float16*)alloc(196608*2);
  _Float16* wf_hh1  = (_Float16*)alloc(196608*2);
  _Float16* wf_ih2  = (_Float16*)alloc(196608*2);
  _Float16* wf_hh2  = (_Float16*)alloc(196608*2);
  float*    hc1     = (float*)   alloc(256*256*4);
  float*    hc2     = (float*)   alloc(256*256*4);
  int*      flag1   = (int*)     alloc(16*4);
  int*      flag2   = (int*)     alloc(32*4);
  int*      flag3   = (int*)     alloc(16*4);
  _Float16* gi1     = (_Float16*)alloc((size_t)512*393216);   // 201 MB
  _Float16* h1seq   = (_Float16*)alloc((size_t)512*131072);   //  67 MB
  _Float16* gi2     = (_Float16*)alloc((size_t)64*393216);    //  25 MB ring

  k_maxabs<<<128, 256, 0, stream>>>(w_ih1, w_hh1, w_ih2, w_hh2, 196608, slots);
  k_quant <<<3072, 256, 0, stream>>>(w_ih1, w_hh1, w_ih2, w_hh2, slots,
                                     wf_ih1, wf_hh1, wf_ih2, wf_hh2);
  (void)hipMemcpyAsync(hc1, h1_0, 256*256*4, hipMemcpyDeviceToDevice, stream);
  (void)hipMemcpyAsync(hc2, h2_0, 256*256*4, hipMemcpyDeviceToDevice, stream);

  dim3 gg(2048, 6);
  k_gemm_f32<<<gg, 256, 0, stream>>>(x, wf_ih1, b_ih1, b_hh1, gi1);

  k_pipe<<<64, 1024, 0, stream>>>(gi1, wf_hh1, b_hh1, hc1, h1seq,
                                  wf_ih2, b_ih2, b_hh2, wf_hh2,
                                  hc2, gi2, flag1, flag2, flag3);

  (void)hipMemcpyAsync(d_out, hc2, 256*256*4, hipMemcpyDeviceToDevice, stream);
}